// Round 17
// baseline (511.911 us; speedup 1.0000x reference)
//
#include <hip/hip_runtime.h>

// FNO spectral block: x(32,256,4096), weight(256,256,128,2) -> out (dtype of x).
// probe -> basis -> fwd gemm (radix-2 folded rDFT, async reg-staged K-loop,
// fused pack to interleaved Xp4) -> mix (register double-buffered chunk-4
// prefetch) -> inv gemm (radix-2 folded irDFT, async reg-staged, butterfly).

typedef unsigned short u16;
typedef unsigned int   u32;
typedef __attribute__((ext_vector_type(8))) short bf16x8;
typedef __attribute__((ext_vector_type(4))) float f32x4;

#define MLEN  4096

__device__ __forceinline__ u16 f2b(float f) {           // fp32 -> bf16 RNE
  u32 u = __float_as_uint(f);
  u += 0x7fffu + ((u >> 16) & 1u);
  return (u16)(u >> 16);
}
__device__ __forceinline__ float blo(u32 p) { return __uint_as_float(p << 16); }
__device__ __forceinline__ float bhi(u32 p) { return __uint_as_float(p & 0xffff0000u); }

// ------------------------------------------------------------- dtype probe
__global__ void probe_kernel(const u16* __restrict__ x16, int* __restrict__ flag) {
  __shared__ int cnt;
  if (threadIdx.x == 0) cnt = 0;
  __syncthreads();
  int c = 0;
  for (int j = threadIdx.x; j < 4096; j += 256) {
    u32 e = (x16[j] >> 7) & 0xFFu;
    if (e >= 0x8Fu) ++c;
  }
  atomicAdd(&cnt, c);
  __syncthreads();
  if (threadIdx.x == 0) flag[0] = (cnt > 256) ? 0 : 1;   // 0=fp32, 1=bf16
}

// ---------------------------------------------------------------- basis
__global__ void basis_kernel(u16* __restrict__ Bas1P, u16* __restrict__ Bas2P) {
  int t = blockIdx.x;           // 0..2047
  int c = threadIdx.x;          // 0..255
  {
    int p = c >> 7, rem = c & 127, j = rem >> 1, s2 = rem & 1;
    int m = 2 * j + p;
    int idx = (m * t) & 4095;
    float theta = (float)idx * (6.283185307179586f / 4096.0f);
    float s, cth;
    __sincosf(theta, &s, &cth);
    Bas2P[t * 256 + c] = f2b(s2 ? -s : cth);
  }
  {
    int parity = c >> 7, isim = (c >> 6) & 1, j = c & 63;
    int m = 2 * j + parity;
    int idx = (m * t) & 4095;
    float theta = (float)idx * (6.283185307179586f / 4096.0f);
    float s, cth;
    __sincosf(theta, &s, &cth);
    Bas1P[c * 2048 + t] = f2b(isim ? -s : cth);
  }
}

// ---------------------------------------------------------------- GEMM (NT)
// C = A(MxK,row,lda) * Bt(NxK,row,ldb)^T.  Async reg-staged K-loop (T14):
// stage_load(kt+64) issues global->reg loads overlapping kstep(kt);
// stage_store (fold/cvt + LDS write) runs after the barrier.
// EPI=1: radix-2 inverse, butterfly epilogue.  EPI=2: radix-2 forward,
// A-load folds x[t] +/- x[t+2048], pack into interleaved Xp4.
template <int BM, int BN, int EPI, bool ADUAL>
__global__ __launch_bounds__(256)
void gemm_nt(const void* __restrict__ A, const u16* __restrict__ Bt,
             int K, int lda, int ldb,
             u32* __restrict__ Xp, int ldc,
             const void* __restrict__ xres, void* __restrict__ outp,
             const int* __restrict__ flag) {
  constexpr int LD = 72;                 // 64+8 pad: <=2-way LDS conflicts (free)
  constexpr int FM = BM / 32;
  constexpr int FN = BN / 32;
  constexpr int AITER = (BM * 8) / 256;  // per-thread A stage iterations
  constexpr int BITER = (BN * 8) / 256;
  __shared__ __align__(16) char smem[(BM + BN) * LD * 2];
  u16* As = (u16*)smem;
  u16* Bs = (u16*)(smem + BM * LD * 2);
  const int mode = (ADUAL || EPI == 1) ? flag[0] : 1;
  const int tid = threadIdx.x;
  const int bn0 = blockIdx.x * BN;
  const int bm0 = blockIdx.y * BM;
  const int lane = tid & 63;
  const int wave = tid >> 6;
  const int wm = wave >> 1, wn = wave & 1;
  const int l15 = lane & 15, q4 = lane >> 4;

  const u16* Btb = Bt;
  if constexpr (EPI == 2) Btb += (size_t)blockIdx.z * BN * ldb;

  f32x4 acc[FM][FN] = {};    // EPI==1: even-mode accumulator E
  f32x4 acc2[FM][FN] = {};   // EPI==1: odd-mode accumulator O (else unused/DCE)

  // staging registers (unused variants DCE'd per instantiation)
  uint4  aU[AITER];                      // EPI1 A / EPI2-bf16 (uses [0])
  uint4  a16b;                           // EPI2-bf16 second operand
  float4 af0, af1, ag0, ag1;             // EPI2-fp32 operands
  uint4  bU[BITER];

  auto stage_load = [&](int kt) {
    if constexpr (EPI == 2) {
      const int row = tid >> 3, c8 = tid & 7;   // BM*8 == 256 exactly
      if (mode == 1) {
        const u16* s0 = &((const u16*)A)[(size_t)(bm0 + row) * lda + kt + c8 * 8];
        aU[0] = *(const uint4*)s0;
        a16b  = *(const uint4*)(s0 + 2048);
      } else {
        const float* s0 = &((const float*)A)[(size_t)(bm0 + row) * lda + kt + c8 * 8];
        af0 = *(const float4*)s0;
        af1 = *(const float4*)(s0 + 4);
        ag0 = *(const float4*)(s0 + 2048);
        ag1 = *(const float4*)(s0 + 2052);
      }
    } else {
      const u16* Ab = (const u16*)A;
#pragma unroll
      for (int i = 0; i < AITER; ++i) {
        int q = tid + i * 256, row = q >> 3, c8 = q & 7;
        aU[i] = *(const uint4*)&Ab[(size_t)(bm0 + row) * lda + kt + c8 * 8];
      }
    }
#pragma unroll
    for (int i = 0; i < BITER; ++i) {
      int q = tid + i * 256, row = q >> 3, c8 = q & 7;
      bU[i] = *(const uint4*)&Btb[(size_t)(bn0 + row) * ldb + kt + c8 * 8];
    }
  };

  auto stage_store = [&]() {
    if constexpr (EPI == 2) {
      const int row = tid >> 3, c8 = tid & 7;
      const int neg = blockIdx.z;
      u16 tmp[8];
      if (mode == 1) {
        u32 aw[4] = {aU[0].x, aU[0].y, aU[0].z, aU[0].w};
        u32 bw[4] = {a16b.x, a16b.y, a16b.z, a16b.w};
#pragma unroll
        for (int j = 0; j < 4; ++j) {
          float lo = neg ? (blo(aw[j]) - blo(bw[j])) : (blo(aw[j]) + blo(bw[j]));
          float hi = neg ? (bhi(aw[j]) - bhi(bw[j])) : (bhi(aw[j]) + bhi(bw[j]));
          tmp[2 * j]     = f2b(lo);
          tmp[2 * j + 1] = f2b(hi);
        }
      } else {
        float a[8] = {af0.x, af0.y, af0.z, af0.w, af1.x, af1.y, af1.z, af1.w};
        float b[8] = {ag0.x, ag0.y, ag0.z, ag0.w, ag1.x, ag1.y, ag1.z, ag1.w};
#pragma unroll
        for (int j = 0; j < 8; ++j)
          tmp[j] = f2b(neg ? (a[j] - b[j]) : (a[j] + b[j]));
      }
      *(uint4*)&As[row * LD + c8 * 8] = *(const uint4*)tmp;
    } else {
#pragma unroll
      for (int i = 0; i < AITER; ++i) {
        int q = tid + i * 256, row = q >> 3, c8 = q & 7;
        *(uint4*)&As[row * LD + c8 * 8] = aU[i];
      }
    }
#pragma unroll
    for (int i = 0; i < BITER; ++i) {
      int q = tid + i * 256, row = q >> 3, c8 = q & 7;
      *(uint4*)&Bs[row * LD + c8 * 8] = bU[i];
    }
  };

  // one 64-wide K-step of MFMAs into the given accumulator (static indexing)
  auto kstep = [&](f32x4 (&ac)[FM][FN]) {
#pragma unroll
    for (int kk = 0; kk < 2; ++kk) {
      const int ko = kk * 32 + q4 * 8;
      bf16x8 af[FM], bfr[FN];
#pragma unroll
      for (int mi = 0; mi < FM; ++mi)
        af[mi] = *(const bf16x8*)&As[(wm * (BM / 2) + mi * 16 + l15) * LD + ko];
#pragma unroll
      for (int ni = 0; ni < FN; ++ni)
        bfr[ni] = *(const bf16x8*)&Bs[(wn * (BN / 2) + ni * 16 + l15) * LD + ko];
#pragma unroll
      for (int mi = 0; mi < FM; ++mi)
#pragma unroll
        for (int ni = 0; ni < FN; ++ni)
          ac[mi][ni] = __builtin_amdgcn_mfma_f32_16x16x32_bf16(
              af[mi], bfr[ni], ac[mi][ni], 0, 0, 0);
    }
  };

  stage_load(0);
  for (int kt = 0; kt < K; kt += 64) {
    __syncthreads();               // prev tile's LDS consumers done
    stage_store();
    __syncthreads();
    if (kt + 64 < K) stage_load(kt + 64);   // overlaps kstep below
    if constexpr (EPI == 1) {
      if (kt >= 128) kstep(acc2); else kstep(acc);
    } else {
      kstep(acc);
    }
  }

  // --------------- epilogues (smem reused; As/Bs dead after barrier) -------
  if constexpr (EPI == 1) {
    // acc rows: wm*64+mi*16+q4*4+r ; cols: wn*32+ni*16+l15 (BN=64).
    // Butterfly: col t'=bn0+cc gets E+O, col bn0+2048+cc gets E-O.
    float* Cs = (float*)smem;            // [32][136]: 0..67 sum, 68..135 diff
    const int s = tid >> 3;              // 0..31 staged row
    const int c8 = tid & 7;
#pragma unroll
    for (int mi = 0; mi < FM; ++mi) {
      __syncthreads();
#pragma unroll
      for (int ni = 0; ni < FN; ++ni) {
        float* dst = &Cs[(wm * 16 + q4 * 4) * 136 + wn * 32 + ni * 16 + l15];
#pragma unroll
        for (int r = 0; r < 4; ++r) {
          float e = acc[mi][ni][r], o = acc2[mi][ni][r];
          dst[r * 136]      = e + o;
          dst[r * 136 + 68] = e - o;
        }
      }
      __syncthreads();
      const int gr = bm0 + mi * 16 + s + ((s < 16) ? 0 : (BM / 2 - 16));
      if (mode == 1) {
        const u16* xr16 = (const u16*)xres;
        u16* o16 = (u16*)outp;
#pragma unroll
        for (int h = 0; h < 2; ++h) {
          float4 va = *(const float4*)&Cs[s * 136 + h * 68 + c8 * 8];
          float4 vb = *(const float4*)&Cs[s * 136 + h * 68 + c8 * 8 + 4];
          size_t gidx = (size_t)gr * ldc + bn0 + h * 2048 + c8 * 8;
          uint4 xv = *(const uint4*)&xr16[gidx];
          float cv[8] = {va.x, va.y, va.z, va.w, vb.x, vb.y, vb.z, vb.w};
          u32 xw[4] = {xv.x, xv.y, xv.z, xv.w};
          u16 ov[8];
#pragma unroll
          for (int j = 0; j < 4; ++j) {
            float l0 = cv[2 * j]     >= 0.f ? cv[2 * j]     : 0.2f * cv[2 * j];
            float l1 = cv[2 * j + 1] >= 0.f ? cv[2 * j + 1] : 0.2f * cv[2 * j + 1];
            ov[2 * j]     = f2b(blo(xw[j]) + l0);
            ov[2 * j + 1] = f2b(bhi(xw[j]) + l1);
          }
          *(uint4*)&o16[gidx] = *(const uint4*)ov;
        }
      } else {
        const float* xf = (const float*)xres;
        float* of = (float*)outp;
#pragma unroll
        for (int h = 0; h < 2; ++h) {
          float4 v0 = *(const float4*)&Cs[s * 136 + h * 68 + c8 * 8];
          float4 v1 = *(const float4*)&Cs[s * 136 + h * 68 + c8 * 8 + 4];
          size_t gidx = (size_t)gr * ldc + bn0 + h * 2048 + c8 * 8;
          float4 x0 = *(const float4*)&xf[gidx];
          float4 x1 = *(const float4*)&xf[gidx + 4];
          float4 o0, o1;
          o0.x = x0.x + (v0.x >= 0.f ? v0.x : 0.2f * v0.x);
          o0.y = x0.y + (v0.y >= 0.f ? v0.y : 0.2f * v0.y);
          o0.z = x0.z + (v0.z >= 0.f ? v0.z : 0.2f * v0.z);
          o0.w = x0.w + (v0.w >= 0.f ? v0.w : 0.2f * v0.w);
          o1.x = x1.x + (v1.x >= 0.f ? v1.x : 0.2f * v1.x);
          o1.y = x1.y + (v1.y >= 0.f ? v1.y : 0.2f * v1.y);
          o1.z = x1.z + (v1.z >= 0.f ? v1.z : 0.2f * v1.z);
          o1.w = x1.w + (v1.w >= 0.f ? v1.w : 0.2f * v1.w);
          *(float4*)&of[gidx] = o0;
          *(float4*)&of[gidx + 4] = o1;
        }
      }
    }
  } else {
    // EPI==2: BM=32 (FM=1), BN=128. cols c<64 -> Re(mode 2c+p), c>=64 -> Im.
    // Write into interleaved Xp4: word = ((ic*16 + b/2)*64 + j)*4 + (b&1)*2 + z
    constexpr int LP = 136;              // 128+8 pad
    u16* Ls = (u16*)smem;                // [32][136] bf16 tile
    __syncthreads();
#pragma unroll
    for (int ni = 0; ni < FN; ++ni) {
      u16* dst = &Ls[(wm * 16 + q4 * 4) * LP + wn * 64 + ni * 16 + l15];
#pragma unroll
      for (int r = 0; r < 4; ++r) dst[r * LP] = f2b(acc[0][ni][r]);
    }
    __syncthreads();
    const int b   = bm0 >> 8;
    const int ic0 = bm0 & 255;
    const int j   = tid & 63, ich = tid >> 6;
    const int woff = (b & 1) * 2 + blockIdx.z;
    const int bp   = b >> 1;
#pragma unroll
    for (int i2 = 0; i2 < 8; ++i2) {
      int ic = i2 * 4 + ich;
      u32 v = (u32)Ls[ic * LP + j] | ((u32)Ls[ic * LP + 64 + j] << 16);
      Xp[((((size_t)(ic0 + ic) * 16 + bp) * 64 + j) << 2) + woff] = v;
    }
  }
}

// ---------------------------------------------------------------- mode mix
// Y[b,o,m] = sum_i X[b,i,m]*w[o,i,m] (complex). Block = (o-pair, b-half),
// 1024 thr: wave>>3 -> o_local, wave&7 -> b-pair, lane -> mode pair.
// X: ONE uint4 load per (ic, b-pair).  Register double-buffer: chunk of 4 ic
// prefetched into named regs while the previous chunk computes (8 loads in
// flight per thread).  Writes Yp parity-grouped (re,im), irfft scale folded.
__global__ __launch_bounds__(1024)
void mix_kernel(const u32* __restrict__ Xp, const void* __restrict__ w,
                u16* __restrict__ Yp, const int* __restrict__ flag) {
  const int tid = threadIdx.x;
  const int wave = tid >> 6, lane = tid & 63;
  const int o = blockIdx.x * 2 + (wave >> 3);
  const int bp = blockIdx.y * 8 + (wave & 7);      // b-pair index, b0 = 2*bp
  const int m = lane * 2;
  const int mode = flag[0];

  const uint4* X4 = (const uint4*)Xp + (size_t)bp * 64 + lane;

  float ar[2][2] = {}, ai[2][2] = {};    // [b][parity]

  if (mode == 0) {
    const float* wb = (const float*)w + 2u * ((size_t)o * 32768 + m);
    float4 wA[4], wB[4];
    uint4  xA[4], xB[4];
    auto LDC = [&](float4 (&wv)[4], uint4 (&xv)[4], int c) {
#pragma unroll
      for (int i = 0; i < 4; ++i) {
        wv[i] = *(const float4*)&wb[(size_t)(c * 4 + i) * 256];
        xv[i] = X4[(size_t)(c * 4 + i) * 1024];
      }
    };
    auto CMP = [&](float4 (&wv)[4], uint4 (&xv)[4]) {
#pragma unroll
      for (int i = 0; i < 4; ++i) {
        float wr0 = wv[i].x, wi0 = wv[i].y, wr1 = wv[i].z, wi1 = wv[i].w;
        float xr, xi;
        xr = blo(xv[i].x); xi = bhi(xv[i].x);
        ar[0][0] = fmaf(xr, wr0, fmaf(-xi, wi0, ar[0][0]));
        ai[0][0] = fmaf(xr, wi0, fmaf(xi, wr0, ai[0][0]));
        xr = blo(xv[i].y); xi = bhi(xv[i].y);
        ar[0][1] = fmaf(xr, wr1, fmaf(-xi, wi1, ar[0][1]));
        ai[0][1] = fmaf(xr, wi1, fmaf(xi, wr1, ai[0][1]));
        xr = blo(xv[i].z); xi = bhi(xv[i].z);
        ar[1][0] = fmaf(xr, wr0, fmaf(-xi, wi0, ar[1][0]));
        ai[1][0] = fmaf(xr, wi0, fmaf(xi, wr0, ai[1][0]));
        xr = blo(xv[i].w); xi = bhi(xv[i].w);
        ar[1][1] = fmaf(xr, wr1, fmaf(-xi, wi1, ar[1][1]));
        ai[1][1] = fmaf(xr, wi1, fmaf(xi, wr1, ai[1][1]));
      }
    };
    LDC(wA, xA, 0);
    for (int c = 0; c < 64; c += 2) {    // 64 chunks of 4 ic
      LDC(wB, xB, c + 1);
      CMP(wA, xA);
      if (c + 2 < 64) LDC(wA, xA, c + 2);
      CMP(wB, xB);
    }
  } else {
    const u32* wb = (const u32*)w + (size_t)o * 32768 + m;
    uint2 wA[4], wB[4];
    uint4 xA[4], xB[4];
    auto LDC = [&](uint2 (&wv)[4], uint4 (&xv)[4], int c) {
#pragma unroll
      for (int i = 0; i < 4; ++i) {
        wv[i] = *(const uint2*)&wb[(size_t)(c * 4 + i) * 128];
        xv[i] = X4[(size_t)(c * 4 + i) * 1024];
      }
    };
    auto CMP = [&](uint2 (&wv)[4], uint4 (&xv)[4]) {
#pragma unroll
      for (int i = 0; i < 4; ++i) {
        float wr0 = blo(wv[i].x), wi0 = bhi(wv[i].x);
        float wr1 = blo(wv[i].y), wi1 = bhi(wv[i].y);
        float xr, xi;
        xr = blo(xv[i].x); xi = bhi(xv[i].x);
        ar[0][0] = fmaf(xr, wr0, fmaf(-xi, wi0, ar[0][0]));
        ai[0][0] = fmaf(xr, wi0, fmaf(xi, wr0, ai[0][0]));
        xr = blo(xv[i].y); xi = bhi(xv[i].y);
        ar[0][1] = fmaf(xr, wr1, fmaf(-xi, wi1, ar[0][1]));
        ai[0][1] = fmaf(xr, wi1, fmaf(xi, wr1, ai[0][1]));
        xr = blo(xv[i].z); xi = bhi(xv[i].z);
        ar[1][0] = fmaf(xr, wr0, fmaf(-xi, wi0, ar[1][0]));
        ai[1][0] = fmaf(xr, wi0, fmaf(xi, wr0, ai[1][0]));
        xr = blo(xv[i].w); xi = bhi(xv[i].w);
        ar[1][1] = fmaf(xr, wr1, fmaf(-xi, wi1, ar[1][1]));
        ai[1][1] = fmaf(xr, wi1, fmaf(xi, wr1, ai[1][1]));
      }
    };
    LDC(wA, xA, 0);
    for (int c = 0; c < 64; c += 2) {
      LDC(wB, xB, c + 1);
      CMP(wA, xA);
      if (c + 2 < 64) LDC(wA, xA, c + 2);
      CMP(wB, xB);
    }
  }

  const float sIm = 2.0f / 4096.0f;
  const float sRe0 = (m == 0) ? (1.0f / 4096.0f) : (2.0f / 4096.0f);
  const float sRe1 = 2.0f / 4096.0f;
  u32* Yp32 = (u32*)Yp;
#pragma unroll
  for (int jb = 0; jb < 2; ++jb) {
    int b = bp * 2 + jb;
    size_t base = ((size_t)(b * 256 + o)) * 128;   // u32 index
    u32 we = (u32)f2b(ar[jb][0] * sRe0) | ((u32)f2b(ai[jb][0] * sIm) << 16);
    u32 wo = (u32)f2b(ar[jb][1] * sRe1) | ((u32)f2b(ai[jb][1] * sIm) << 16);
    Yp32[base + lane] = we;          // even-mode (re,im) pair, word lane
    Yp32[base + 64 + lane] = wo;     // odd-mode  (re,im) pair, word 64+lane
  }
}

// ---------------------------------------------------------------- launch
extern "C" void kernel_launch(void* const* d_in, const int* in_sizes, int n_in,
                              void* d_out, int out_size, void* d_ws, size_t ws_size,
                              hipStream_t stream) {
  const void* x = d_in[0];                // (32,256,4096) fp32 or bf16
  const void* w = d_in[1];                // (256,256,128,2) fp32 or bf16

  char* ws = (char*)d_ws;
  int*  flag  = (int*)(ws);
  u16*  Bas1P = (u16*)(ws + (1u << 20)); // 1 MB  [r=256][t'=2048] fwd parity
  u16*  Bas2P = (u16*)(ws + (2u << 20)); // 1 MB  [t'=2048][c=256] inv parity
  u32*  Xp4   = (u32*)(ws + (4u << 20)); // 4 MB  [ic][bp][j] uint4(e0,o0,e1,o1)
  u16*  Yp    = (u16*)(ws + (8u << 20)); // 4 MB  parity-grouped (re,im)

  probe_kernel<<<dim3(1), dim3(256), 0, stream>>>((const u16*)x, flag);
  basis_kernel<<<dim3(2048), dim3(256), 0, stream>>>(Bas1P, Bas2P);

  // radix-2 folded forward rDFT: z=parity, K=2048, fused pack into Xp4
  gemm_nt<32, 128, 2, true><<<dim3(1, 256, 2), dim3(256), 0, stream>>>(
      x, Bas1P, 2048, MLEN, 2048, Xp4, 0, nullptr, nullptr, flag);

  // per-mode complex channel mix -> Yp (bf16, irfft scaling folded in)
  mix_kernel<<<dim3(128, 2), dim3(1024), 0, stream>>>(Xp4, w, Yp, flag);

  // radix-2 folded inverse DFT + LeakyReLU + residual (butterfly epilogue)
  gemm_nt<128, 64, 1, false><<<dim3(32, 64, 1), dim3(256), 0, stream>>>(
      Yp, Bas2P, 256, 256, 256, nullptr, MLEN, x, d_out, flag);
}

// Round 18
// 464.284 us; speedup vs baseline: 1.1026x; 1.1026x over previous
//
#include <hip/hip_runtime.h>

// FNO spectral block: x(32,256,4096), weight(256,256,128,2) -> out (dtype of x).
// probe -> basis -> fwd gemm (radix-2 folded rDFT, fused pack to interleaved
// Xp4[ic][bp][j] = uint4(e_b0,o_b0,e_b1,o_b1)) -> mix (1 uint4 X load/iter,
// register double-buffered chunk-4 prefetch) -> inv gemm (radix-2 folded
// irDFT, butterfly epilogue).  [round-17 T14 staging reverted: it spilled]

typedef unsigned short u16;
typedef unsigned int   u32;
typedef __attribute__((ext_vector_type(8))) short bf16x8;
typedef __attribute__((ext_vector_type(4))) float f32x4;

#define MLEN  4096

__device__ __forceinline__ u16 f2b(float f) {           // fp32 -> bf16 RNE
  u32 u = __float_as_uint(f);
  u += 0x7fffu + ((u >> 16) & 1u);
  return (u16)(u >> 16);
}
__device__ __forceinline__ float blo(u32 p) { return __uint_as_float(p << 16); }
__device__ __forceinline__ float bhi(u32 p) { return __uint_as_float(p & 0xffff0000u); }

// ------------------------------------------------------------- dtype probe
__global__ void probe_kernel(const u16* __restrict__ x16, int* __restrict__ flag) {
  __shared__ int cnt;
  if (threadIdx.x == 0) cnt = 0;
  __syncthreads();
  int c = 0;
  for (int j = threadIdx.x; j < 4096; j += 256) {
    u32 e = (x16[j] >> 7) & 0xFFu;
    if (e >= 0x8Fu) ++c;
  }
  atomicAdd(&cnt, c);
  __syncthreads();
  if (threadIdx.x == 0) flag[0] = (cnt > 256) ? 0 : 1;   // 0=fp32, 1=bf16
}

// ---------------------------------------------------------------- basis
__global__ void basis_kernel(u16* __restrict__ Bas1P, u16* __restrict__ Bas2P) {
  int t = blockIdx.x;           // 0..2047
  int c = threadIdx.x;          // 0..255
  {
    int p = c >> 7, rem = c & 127, j = rem >> 1, s2 = rem & 1;
    int m = 2 * j + p;
    int idx = (m * t) & 4095;
    float theta = (float)idx * (6.283185307179586f / 4096.0f);
    float s, cth;
    __sincosf(theta, &s, &cth);
    Bas2P[t * 256 + c] = f2b(s2 ? -s : cth);
  }
  {
    int parity = c >> 7, isim = (c >> 6) & 1, j = c & 63;
    int m = 2 * j + parity;
    int idx = (m * t) & 4095;
    float theta = (float)idx * (6.283185307179586f / 4096.0f);
    float s, cth;
    __sincosf(theta, &s, &cth);
    Bas1P[c * 2048 + t] = f2b(isim ? -s : cth);
  }
}

// ---------------------------------------------------------------- GEMM (NT)
// C = A(MxK,row,lda) * Bt(NxK,row,ldb)^T.
// EPI=1: radix-2 inverse. K=256: kt<128 -> accE (even modes), kt>=128 -> accO.
//        Epilogue: out[gr][bn0+t'] = x + lrelu(E+O); out[gr][bn0+2048+t'] =
//        x + lrelu(E-O). LDS-staged, float4/uint4 IO.
// EPI=2: radix-2 forward: p=blockIdx.z parity; A-load folds
//        a = x[t] +/- x[t+2048]; pack C into interleaved Xp4:
//        u32 word index = (((ic)*16 + b/2)*64 + j)*4 + (b&1)*2 + p.
template <int BM, int BN, int EPI, bool ADUAL>
__global__ __launch_bounds__(256)
void gemm_nt(const void* __restrict__ A, const u16* __restrict__ Bt,
             int K, int lda, int ldb,
             u32* __restrict__ Xp, int ldc,
             const void* __restrict__ xres, void* __restrict__ outp,
             const int* __restrict__ flag) {
  constexpr int LD = 72;                 // 64+8 pad: <=2-way LDS conflicts (free)
  constexpr int FM = BM / 32;
  constexpr int FN = BN / 32;
  __shared__ __align__(16) char smem[(BM + BN) * LD * 2];
  u16* As = (u16*)smem;
  u16* Bs = (u16*)(smem + BM * LD * 2);
  const int mode = (ADUAL || EPI == 1) ? flag[0] : 1;
  const int tid = threadIdx.x;
  const int bn0 = blockIdx.x * BN;
  const int bm0 = blockIdx.y * BM;
  const int lane = tid & 63;
  const int wave = tid >> 6;
  const int wm = wave >> 1, wn = wave & 1;
  const int l15 = lane & 15, q4 = lane >> 4;

  const u16* Btb = Bt;
  if constexpr (EPI == 2) Btb += (size_t)blockIdx.z * BN * ldb;

  f32x4 acc[FM][FN] = {};    // EPI==1: even-mode accumulator E
  f32x4 acc2[FM][FN] = {};   // EPI==1: odd-mode accumulator O (else unused/DCE)

  // one 64-wide K-step of MFMAs into the given accumulator (static indexing)
  auto kstep = [&](f32x4 (&ac)[FM][FN]) {
#pragma unroll
    for (int kk = 0; kk < 2; ++kk) {
      const int ko = kk * 32 + q4 * 8;
      bf16x8 af[FM], bfr[FN];
#pragma unroll
      for (int mi = 0; mi < FM; ++mi)
        af[mi] = *(const bf16x8*)&As[(wm * (BM / 2) + mi * 16 + l15) * LD + ko];
#pragma unroll
      for (int ni = 0; ni < FN; ++ni)
        bfr[ni] = *(const bf16x8*)&Bs[(wn * (BN / 2) + ni * 16 + l15) * LD + ko];
#pragma unroll
      for (int mi = 0; mi < FM; ++mi)
#pragma unroll
        for (int ni = 0; ni < FN; ++ni)
          ac[mi][ni] = __builtin_amdgcn_mfma_f32_16x16x32_bf16(
              af[mi], bfr[ni], ac[mi][ni], 0, 0, 0);
    }
  };

  for (int kt = 0; kt < K; kt += 64) {
    __syncthreads();
    if constexpr (EPI == 2) {
      // radix-2 fold: a = x[row][kt+c] +/- x[row][kt+2048+c]
      const int neg = blockIdx.z;
#pragma unroll
      for (int q = tid; q < BM * 8; q += 256) {
        int row = q >> 3, c8 = q & 7;
        u16 tmp[8];
        if (mode == 1) {
          const u16* s0 = &((const u16*)A)[(size_t)(bm0 + row) * lda + kt + c8 * 8];
          uint4 a0 = *(const uint4*)s0;
          uint4 a1 = *(const uint4*)(s0 + 2048);
          u32 aw[4] = {a0.x, a0.y, a0.z, a0.w};
          u32 bw[4] = {a1.x, a1.y, a1.z, a1.w};
#pragma unroll
          for (int j = 0; j < 4; ++j) {
            float lo = neg ? (blo(aw[j]) - blo(bw[j])) : (blo(aw[j]) + blo(bw[j]));
            float hi = neg ? (bhi(aw[j]) - bhi(bw[j])) : (bhi(aw[j]) + bhi(bw[j]));
            tmp[2 * j]     = f2b(lo);
            tmp[2 * j + 1] = f2b(hi);
          }
        } else {
          const float* s0 = &((const float*)A)[(size_t)(bm0 + row) * lda + kt + c8 * 8];
          float4 f0 = *(const float4*)s0;
          float4 f1 = *(const float4*)(s0 + 4);
          float4 g0 = *(const float4*)(s0 + 2048);
          float4 g1 = *(const float4*)(s0 + 2052);
          float a[8] = {f0.x, f0.y, f0.z, f0.w, f1.x, f1.y, f1.z, f1.w};
          float b[8] = {g0.x, g0.y, g0.z, g0.w, g1.x, g1.y, g1.z, g1.w};
#pragma unroll
          for (int j = 0; j < 8; ++j)
            tmp[j] = f2b(neg ? (a[j] - b[j]) : (a[j] + b[j]));
        }
        *(uint4*)&As[row * LD + c8 * 8] = *(const uint4*)tmp;
      }
    } else {
      const u16* Ab = (const u16*)A;
#pragma unroll
      for (int q = tid; q < BM * 8; q += 256) {
        int row = q >> 3, c8 = q & 7;
        *(uint4*)&As[row * LD + c8 * 8] =
            *(const uint4*)&Ab[(size_t)(bm0 + row) * lda + kt + c8 * 8];
      }
    }
#pragma unroll
    for (int q = tid; q < BN * 8; q += 256) {
      int row = q >> 3, c8 = q & 7;
      *(uint4*)&Bs[row * LD + c8 * 8] =
          *(const uint4*)&Btb[(size_t)(bn0 + row) * ldb + kt + c8 * 8];
    }
    __syncthreads();
    if constexpr (EPI == 1) {
      if (kt >= 128) kstep(acc2); else kstep(acc);
    } else {
      kstep(acc);
    }
  }

  // --------------- epilogues (smem reused; As/Bs dead after barrier) -------
  if constexpr (EPI == 1) {
    // acc rows: wm*64+mi*16+q4*4+r ; cols: wn*32+ni*16+l15 (BN=64).
    // Butterfly: col t'=bn0+cc gets E+O, col bn0+2048+cc gets E-O.
    float* Cs = (float*)smem;            // [32][136]: 0..67 sum, 68..135 diff
    const int s = tid >> 3;              // 0..31 staged row
    const int c8 = tid & 7;
#pragma unroll
    for (int mi = 0; mi < FM; ++mi) {
      __syncthreads();
#pragma unroll
      for (int ni = 0; ni < FN; ++ni) {
        float* dst = &Cs[(wm * 16 + q4 * 4) * 136 + wn * 32 + ni * 16 + l15];
#pragma unroll
        for (int r = 0; r < 4; ++r) {
          float e = acc[mi][ni][r], o = acc2[mi][ni][r];
          dst[r * 136]      = e + o;
          dst[r * 136 + 68] = e - o;
        }
      }
      __syncthreads();
      const int gr = bm0 + mi * 16 + s + ((s < 16) ? 0 : (BM / 2 - 16));
      if (mode == 1) {
        const u16* xr16 = (const u16*)xres;
        u16* o16 = (u16*)outp;
#pragma unroll
        for (int h = 0; h < 2; ++h) {
          float4 va = *(const float4*)&Cs[s * 136 + h * 68 + c8 * 8];
          float4 vb = *(const float4*)&Cs[s * 136 + h * 68 + c8 * 8 + 4];
          size_t gidx = (size_t)gr * ldc + bn0 + h * 2048 + c8 * 8;
          uint4 xv = *(const uint4*)&xr16[gidx];
          float cv[8] = {va.x, va.y, va.z, va.w, vb.x, vb.y, vb.z, vb.w};
          u32 xw[4] = {xv.x, xv.y, xv.z, xv.w};
          u16 ov[8];
#pragma unroll
          for (int j = 0; j < 4; ++j) {
            float l0 = cv[2 * j]     >= 0.f ? cv[2 * j]     : 0.2f * cv[2 * j];
            float l1 = cv[2 * j + 1] >= 0.f ? cv[2 * j + 1] : 0.2f * cv[2 * j + 1];
            ov[2 * j]     = f2b(blo(xw[j]) + l0);
            ov[2 * j + 1] = f2b(bhi(xw[j]) + l1);
          }
          *(uint4*)&o16[gidx] = *(const uint4*)ov;
        }
      } else {
        const float* xf = (const float*)xres;
        float* of = (float*)outp;
#pragma unroll
        for (int h = 0; h < 2; ++h) {
          float4 v0 = *(const float4*)&Cs[s * 136 + h * 68 + c8 * 8];
          float4 v1 = *(const float4*)&Cs[s * 136 + h * 68 + c8 * 8 + 4];
          size_t gidx = (size_t)gr * ldc + bn0 + h * 2048 + c8 * 8;
          float4 x0 = *(const float4*)&xf[gidx];
          float4 x1 = *(const float4*)&xf[gidx + 4];
          float4 o0, o1;
          o0.x = x0.x + (v0.x >= 0.f ? v0.x : 0.2f * v0.x);
          o0.y = x0.y + (v0.y >= 0.f ? v0.y : 0.2f * v0.y);
          o0.z = x0.z + (v0.z >= 0.f ? v0.z : 0.2f * v0.z);
          o0.w = x0.w + (v0.w >= 0.f ? v0.w : 0.2f * v0.w);
          o1.x = x1.x + (v1.x >= 0.f ? v1.x : 0.2f * v1.x);
          o1.y = x1.y + (v1.y >= 0.f ? v1.y : 0.2f * v1.y);
          o1.z = x1.z + (v1.z >= 0.f ? v1.z : 0.2f * v1.z);
          o1.w = x1.w + (v1.w >= 0.f ? v1.w : 0.2f * v1.w);
          *(float4*)&of[gidx] = o0;
          *(float4*)&of[gidx + 4] = o1;
        }
      }
    }
  } else {
    // EPI==2: BM=32 (FM=1), BN=128. cols c<64 -> Re(mode 2c+p), c>=64 -> Im.
    // Write into interleaved Xp4: word = ((ic*16 + b/2)*64 + j)*4 + (b&1)*2 + z
    constexpr int LP = 136;              // 128+8 pad
    u16* Ls = (u16*)smem;                // [32][136] bf16 tile
    __syncthreads();
#pragma unroll
    for (int ni = 0; ni < FN; ++ni) {
      u16* dst = &Ls[(wm * 16 + q4 * 4) * LP + wn * 64 + ni * 16 + l15];
#pragma unroll
      for (int r = 0; r < 4; ++r) dst[r * LP] = f2b(acc[0][ni][r]);
    }
    __syncthreads();
    const int b   = bm0 >> 8;
    const int ic0 = bm0 & 255;
    const int j   = tid & 63, ich = tid >> 6;
    const int woff = (b & 1) * 2 + blockIdx.z;
    const int bp   = b >> 1;
#pragma unroll
    for (int i2 = 0; i2 < 8; ++i2) {
      int ic = i2 * 4 + ich;
      u32 v = (u32)Ls[ic * LP + j] | ((u32)Ls[ic * LP + 64 + j] << 16);
      Xp[((((size_t)(ic0 + ic) * 16 + bp) * 64 + j) << 2) + woff] = v;
    }
  }
}

// ---------------------------------------------------------------- mode mix
// Y[b,o,m] = sum_i X[b,i,m]*w[o,i,m] (complex). Block = (o-pair, b-half),
// 1024 thr: wave>>3 -> o_local, wave&7 -> b-pair, lane -> mode pair.
// X: ONE uint4 load per (ic, b-pair).  Register double-buffer: chunk of 4 ic
// prefetched into named regs while the previous chunk computes (8 loads in
// flight per thread).  Writes Yp parity-grouped (re,im), irfft scale folded.
__global__ __launch_bounds__(1024)
void mix_kernel(const u32* __restrict__ Xp, const void* __restrict__ w,
                u16* __restrict__ Yp, const int* __restrict__ flag) {
  const int tid = threadIdx.x;
  const int wave = tid >> 6, lane = tid & 63;
  const int o = blockIdx.x * 2 + (wave >> 3);
  const int bp = blockIdx.y * 8 + (wave & 7);      // b-pair index, b0 = 2*bp
  const int m = lane * 2;
  const int mode = flag[0];

  const uint4* X4 = (const uint4*)Xp + (size_t)bp * 64 + lane;

  float ar[2][2] = {}, ai[2][2] = {};    // [b][parity]

  if (mode == 0) {
    const float* wb = (const float*)w + 2u * ((size_t)o * 32768 + m);
    float4 wA[4], wB[4];
    uint4  xA[4], xB[4];
    auto LDC = [&](float4 (&wv)[4], uint4 (&xv)[4], int c) {
#pragma unroll
      for (int i = 0; i < 4; ++i) {
        wv[i] = *(const float4*)&wb[(size_t)(c * 4 + i) * 256];
        xv[i] = X4[(size_t)(c * 4 + i) * 1024];
      }
    };
    auto CMP = [&](float4 (&wv)[4], uint4 (&xv)[4]) {
#pragma unroll
      for (int i = 0; i < 4; ++i) {
        float wr0 = wv[i].x, wi0 = wv[i].y, wr1 = wv[i].z, wi1 = wv[i].w;
        float xr, xi;
        xr = blo(xv[i].x); xi = bhi(xv[i].x);
        ar[0][0] = fmaf(xr, wr0, fmaf(-xi, wi0, ar[0][0]));
        ai[0][0] = fmaf(xr, wi0, fmaf(xi, wr0, ai[0][0]));
        xr = blo(xv[i].y); xi = bhi(xv[i].y);
        ar[0][1] = fmaf(xr, wr1, fmaf(-xi, wi1, ar[0][1]));
        ai[0][1] = fmaf(xr, wi1, fmaf(xi, wr1, ai[0][1]));
        xr = blo(xv[i].z); xi = bhi(xv[i].z);
        ar[1][0] = fmaf(xr, wr0, fmaf(-xi, wi0, ar[1][0]));
        ai[1][0] = fmaf(xr, wi0, fmaf(xi, wr0, ai[1][0]));
        xr = blo(xv[i].w); xi = bhi(xv[i].w);
        ar[1][1] = fmaf(xr, wr1, fmaf(-xi, wi1, ar[1][1]));
        ai[1][1] = fmaf(xr, wi1, fmaf(xi, wr1, ai[1][1]));
      }
    };
    LDC(wA, xA, 0);
    for (int c = 0; c < 64; c += 2) {    // 64 chunks of 4 ic
      LDC(wB, xB, c + 1);
      CMP(wA, xA);
      if (c + 2 < 64) LDC(wA, xA, c + 2);
      CMP(wB, xB);
    }
  } else {
    const u32* wb = (const u32*)w + (size_t)o * 32768 + m;
    uint2 wA[4], wB[4];
    uint4 xA[4], xB[4];
    auto LDC = [&](uint2 (&wv)[4], uint4 (&xv)[4], int c) {
#pragma unroll
      for (int i = 0; i < 4; ++i) {
        wv[i] = *(const uint2*)&wb[(size_t)(c * 4 + i) * 128];
        xv[i] = X4[(size_t)(c * 4 + i) * 1024];
      }
    };
    auto CMP = [&](uint2 (&wv)[4], uint4 (&xv)[4]) {
#pragma unroll
      for (int i = 0; i < 4; ++i) {
        float wr0 = blo(wv[i].x), wi0 = bhi(wv[i].x);
        float wr1 = blo(wv[i].y), wi1 = bhi(wv[i].y);
        float xr, xi;
        xr = blo(xv[i].x); xi = bhi(xv[i].x);
        ar[0][0] = fmaf(xr, wr0, fmaf(-xi, wi0, ar[0][0]));
        ai[0][0] = fmaf(xr, wi0, fmaf(xi, wr0, ai[0][0]));
        xr = blo(xv[i].y); xi = bhi(xv[i].y);
        ar[0][1] = fmaf(xr, wr1, fmaf(-xi, wi1, ar[0][1]));
        ai[0][1] = fmaf(xr, wi1, fmaf(xi, wr1, ai[0][1]));
        xr = blo(xv[i].z); xi = bhi(xv[i].z);
        ar[1][0] = fmaf(xr, wr0, fmaf(-xi, wi0, ar[1][0]));
        ai[1][0] = fmaf(xr, wi0, fmaf(xi, wr0, ai[1][0]));
        xr = blo(xv[i].w); xi = bhi(xv[i].w);
        ar[1][1] = fmaf(xr, wr1, fmaf(-xi, wi1, ar[1][1]));
        ai[1][1] = fmaf(xr, wi1, fmaf(xi, wr1, ai[1][1]));
      }
    };
    LDC(wA, xA, 0);
    for (int c = 0; c < 64; c += 2) {
      LDC(wB, xB, c + 1);
      CMP(wA, xA);
      if (c + 2 < 64) LDC(wA, xA, c + 2);
      CMP(wB, xB);
    }
  }

  const float sIm = 2.0f / 4096.0f;
  const float sRe0 = (m == 0) ? (1.0f / 4096.0f) : (2.0f / 4096.0f);
  const float sRe1 = 2.0f / 4096.0f;
  u32* Yp32 = (u32*)Yp;
#pragma unroll
  for (int jb = 0; jb < 2; ++jb) {
    int b = bp * 2 + jb;
    size_t base = ((size_t)(b * 256 + o)) * 128;   // u32 index
    u32 we = (u32)f2b(ar[jb][0] * sRe0) | ((u32)f2b(ai[jb][0] * sIm) << 16);
    u32 wo = (u32)f2b(ar[jb][1] * sRe1) | ((u32)f2b(ai[jb][1] * sIm) << 16);
    Yp32[base + lane] = we;          // even-mode (re,im) pair, word lane
    Yp32[base + 64 + lane] = wo;     // odd-mode  (re,im) pair, word 64+lane
  }
}

// ---------------------------------------------------------------- launch
extern "C" void kernel_launch(void* const* d_in, const int* in_sizes, int n_in,
                              void* d_out, int out_size, void* d_ws, size_t ws_size,
                              hipStream_t stream) {
  const void* x = d_in[0];                // (32,256,4096) fp32 or bf16
  const void* w = d_in[1];                // (256,256,128,2) fp32 or bf16

  char* ws = (char*)d_ws;
  int*  flag  = (int*)(ws);
  u16*  Bas1P = (u16*)(ws + (1u << 20)); // 1 MB  [r=256][t'=2048] fwd parity
  u16*  Bas2P = (u16*)(ws + (2u << 20)); // 1 MB  [t'=2048][c=256] inv parity
  u32*  Xp4   = (u32*)(ws + (4u << 20)); // 4 MB  [ic][bp][j] uint4(e0,o0,e1,o1)
  u16*  Yp    = (u16*)(ws + (8u << 20)); // 4 MB  parity-grouped (re,im)

  probe_kernel<<<dim3(1), dim3(256), 0, stream>>>((const u16*)x, flag);
  basis_kernel<<<dim3(2048), dim3(256), 0, stream>>>(Bas1P, Bas2P);

  // radix-2 folded forward rDFT: z=parity, K=2048, fused pack into Xp4
  gemm_nt<32, 128, 2, true><<<dim3(1, 256, 2), dim3(256), 0, stream>>>(
      x, Bas1P, 2048, MLEN, 2048, Xp4, 0, nullptr, nullptr, flag);

  // per-mode complex channel mix -> Yp (bf16, irfft scaling folded in)
  mix_kernel<<<dim3(128, 2), dim3(1024), 0, stream>>>(Xp4, w, Yp, flag);

  // radix-2 folded inverse DFT + LeakyReLU + residual (butterfly epilogue)
  gemm_nt<128, 64, 1, false><<<dim3(32, 64, 1), dim3(256), 0, stream>>>(
      Yp, Bas2P, 256, 256, 256, nullptr, MLEN, x, d_out, flag);
}